// Round 1
// baseline (447.925 us; speedup 1.0000x reference)
//
#include <hip/hip_runtime.h>

#define DM   1024
#define DFF  4096
#define NH   16
#define HD   64
#define TT   2048
#define BT   4096   // B*T

typedef unsigned short u16;
typedef unsigned int   u32;
typedef __attribute__((ext_vector_type(8))) short s16x8;
typedef __attribute__((ext_vector_type(4))) float f32x4;

__device__ __forceinline__ u16 f2bf(float f) {
  u32 u = __builtin_bit_cast(u32, f);
  u += 0x7fffu + ((u >> 16) & 1u);
  return (u16)(u >> 16);
}

// async global->LDS, 16B per lane. HW semantics: dest = wave-uniform base + lane*16.
__device__ __forceinline__ void gl2lds16(const void* g, void* l) {
  __builtin_amdgcn_global_load_lds((__attribute__((address_space(1))) void*)(g),
                                   (__attribute__((address_space(3))) void*)(l),
                                   16, 0, 0);
}

// ---------------- RMSNorm: x fp32 [BT][DM] -> xn bf16 ----------------
__global__ __launch_bounds__(256) void rmsnorm_k(const float* __restrict__ x,
                                                 const float* __restrict__ w,
                                                 u16* __restrict__ xn) {
  const int row = blockIdx.x;
  const int t = threadIdx.x;
  const float4 v = ((const float4*)(x + (size_t)row * DM))[t];
  float ss = v.x*v.x + v.y*v.y + v.z*v.z + v.w*v.w;
  #pragma unroll
  for (int off = 32; off; off >>= 1) ss += __shfl_xor(ss, off, 64);
  __shared__ float red[4];
  if ((t & 63) == 0) red[t >> 6] = ss;
  __syncthreads();
  const float tot = red[0] + red[1] + red[2] + red[3];
  const float r = __builtin_amdgcn_rsqf(tot * (1.0f / DM) + 1.1920929e-7f);
  const float4 wv = ((const float4*)w)[t];
  u16* o = xn + (size_t)row * DM + t * 4;
  o[0] = f2bf(v.x * r * wv.x);
  o[1] = f2bf(v.y * r * wv.y);
  o[2] = f2bf(v.z * r * wv.z);
  o[3] = f2bf(v.w * r * wv.w);
}

// ------------- weight transpose+cvt: W fp32 [K][N] -> Wt bf16 [N][K] -------------
__global__ __launch_bounds__(256) void wtrans_k(const float* __restrict__ W,
                                                u16* __restrict__ Wt,
                                                int K, int N) {
  __shared__ float tile[32][33];
  const int n0 = blockIdx.x * 32, k0 = blockIdx.y * 32;
  const int tx = threadIdx.x, ty = threadIdx.y;  // (32,8)
  #pragma unroll
  for (int i = 0; i < 4; ++i)
    tile[ty + i*8][tx] = W[(size_t)(k0 + ty + i*8) * N + n0 + tx];
  __syncthreads();
  #pragma unroll
  for (int i = 0; i < 4; ++i)
    Wt[(size_t)(n0 + ty + i*8) * K + k0 + tx] = f2bf(tile[tx][ty + i*8]);
}

// ---------------- GEMM: C[M][N] = A[M][K] * Bt[N][K]^T  (bf16 in, fp32 acc) -----
// MODE 0: out bf16;  1: silu->bf16;  2: out fp32;  3: out fp32 = acc+add1+add2
template <int MODE>
__global__ __launch_bounds__(256, 2) void gemm_k(const u16* __restrict__ A,
                                                 const u16* __restrict__ Bt,
                                                 void* __restrict__ Cv,
                                                 int K, int N,
                                                 const float* __restrict__ add1,
                                                 const float* __restrict__ add2) {
  __shared__ u16 sA[128 * 32];
  __shared__ u16 sB[128 * 32];
  const int t = threadIdx.x;
  const int lane = t & 63, wave = t >> 6;
  const int quad = lane >> 4, l4 = lane & 15;
  const int wy = wave >> 1, wx = wave & 1;
  const size_t mBase = (size_t)blockIdx.y * 128;
  const size_t nBase = (size_t)blockIdx.x * 128;
  const int r  = t >> 2;          // 0..63
  const int c8 = (t & 3) * 8;     // 0,8,16,24
  const u16* Ag0 = A + (mBase + r) * K + c8;
  const u16* Ag1 = Ag0 + (size_t)64 * K;
  const u16* Bg0 = Bt + (nBase + r) * K + c8;
  const u16* Bg1 = Bg0 + (size_t)64 * K;
  char* sAb = (char*)sA + (wave << 10);   // wave-uniform LDS base
  char* sBb = (char*)sB + (wave << 10);

  f32x4 acc[4][4];
  #pragma unroll
  for (int i = 0; i < 4; ++i)
    #pragma unroll
    for (int j = 0; j < 4; ++j)
      acc[i][j] = (f32x4)0.0f;

  for (int k0 = 0; k0 < K; k0 += 32) {
    __syncthreads();
    gl2lds16(Ag0 + k0, sAb);
    gl2lds16(Ag1 + k0, sAb + 4096);
    gl2lds16(Bg0 + k0, sBb);
    gl2lds16(Bg1 + k0, sBb + 4096);
    __syncthreads();
    s16x8 af[4], bfr[4];
    #pragma unroll
    for (int i = 0; i < 4; ++i)
      af[i] = *(const s16x8*)&sA[(wy*64 + i*16 + l4) * 32 + quad*8];
    #pragma unroll
    for (int j = 0; j < 4; ++j)
      bfr[j] = *(const s16x8*)&sB[(wx*64 + j*16 + l4) * 32 + quad*8];
    #pragma unroll
    for (int i = 0; i < 4; ++i)
      #pragma unroll
      for (int j = 0; j < 4; ++j)
        acc[i][j] = __builtin_amdgcn_mfma_f32_16x16x32_bf16(af[i], bfr[j], acc[i][j], 0, 0, 0);
  }

  #pragma unroll
  for (int i = 0; i < 4; ++i) {
    const size_t row0 = mBase + wy*64 + i*16 + quad*4;
    #pragma unroll
    for (int j = 0; j < 4; ++j) {
      const int col = (int)nBase + wx*64 + j*16 + l4;
      #pragma unroll
      for (int rg = 0; rg < 4; ++rg) {
        float v = acc[i][j][rg];
        const size_t idx = (row0 + rg) * (size_t)N + col;
        if (MODE == 0) {
          ((u16*)Cv)[idx] = f2bf(v);
        } else if (MODE == 1) {
          v = v / (1.0f + __expf(-v));
          ((u16*)Cv)[idx] = f2bf(v);
        } else if (MODE == 2) {
          ((float*)Cv)[idx] = v;
        } else {
          ((float*)Cv)[idx] = v + add1[idx] + add2[idx];
        }
      }
    }
  }
}

// ---------------- causal flash attention ----------------
// qkv bf16 [BT][3072] (cols: q|k|v, each head h at h*64), out bf16 [BT][DM]
__global__ __launch_bounds__(256, 2) void attn_k(const u16* __restrict__ qkv,
                                                 u16* __restrict__ ao) {
  const int bh = blockIdx.y, b = bh >> 4, h = bh & 15;
  const int t = threadIdx.x, wave = t >> 6, lane = t & 63;
  const int quad = lane >> 4, l4 = lane & 15;
  const int q0 = blockIdx.x * 128;
  const int qw = q0 + wave * 32;           // this wave's 32 q rows
  const u16* Qp = qkv + (size_t)b * TT * 3072 + h * HD;
  const u16* Kp = Qp + DM;
  const u16* Vp = Qp + 2 * DM;

  __shared__ u16 Vt[64][72];               // V^T tile: [d][key]
  __shared__ u16 Pb[4][32][72];            // per-wave P: [q][key]

  // Q fragments (A layout): lane holds Q[qw+mi*16+l4][kf*32+quad*8 .. +7]
  s16x8 qf[2][2];
  #pragma unroll
  for (int mi = 0; mi < 2; ++mi)
    #pragma unroll
    for (int kf = 0; kf < 2; ++kf)
      qf[mi][kf] = *(const s16x8*)(Qp + (size_t)(qw + mi*16 + l4) * 3072 + kf*32 + quad*8);

  float m_run[2][4], l_run[2][4];
  f32x4 o[2][4];
  #pragma unroll
  for (int mi = 0; mi < 2; ++mi) {
    #pragma unroll
    for (int rg = 0; rg < 4; ++rg) { m_run[mi][rg] = -1e30f; l_run[mi][rg] = 0.0f; }
    #pragma unroll
    for (int ni = 0; ni < 4; ++ni) o[mi][ni] = (f32x4)0.0f;
  }

  const int nkt = (q0 >> 6) + 2;           // causal: keys 0 .. q0+127
  const float cs = 0.18033688011f;         // (1/sqrt(64)) * log2(e)

  for (int kt = 0; kt < nkt; ++kt) {
    const int k0 = kt * 64;
    __syncthreads();
    { // cooperative V tile load, transposed into LDS
      const int key = t >> 2, d0 = (t & 3) * 16;
      const u16* vr = Vp + (size_t)(k0 + key) * 3072 + d0;
      u16 vv[16];
      *(s16x8*)&vv[0] = *(const s16x8*)vr;
      *(s16x8*)&vv[8] = *(const s16x8*)(vr + 8);
      #pragma unroll
      for (int e = 0; e < 16; ++e) Vt[d0 + e][key] = vv[e];
    }
    __syncthreads();

    if (k0 <= qw + 31) {
      // S = Q K^T   (C layout: row q = quad*4+rg, col key = l4)
      f32x4 s[2][4];
      #pragma unroll
      for (int nj = 0; nj < 4; ++nj) {
        const u16* kr = Kp + (size_t)(k0 + nj*16 + l4) * 3072 + quad*8;
        const s16x8 kf0 = *(const s16x8*)kr;
        const s16x8 kf1 = *(const s16x8*)(kr + 32);
        #pragma unroll
        for (int mi = 0; mi < 2; ++mi) {
          f32x4 a = (f32x4)0.0f;
          a = __builtin_amdgcn_mfma_f32_16x16x32_bf16(qf[mi][0], kf0, a, 0, 0, 0);
          a = __builtin_amdgcn_mfma_f32_16x16x32_bf16(qf[mi][1], kf1, a, 0, 0, 0);
          s[mi][nj] = a;
        }
      }
      if (k0 + 63 > qw) {  // causal mask needed on this tile
        #pragma unroll
        for (int mi = 0; mi < 2; ++mi)
          #pragma unroll
          for (int nj = 0; nj < 4; ++nj)
            #pragma unroll
            for (int rg = 0; rg < 4; ++rg) {
              const int q = qw + mi*16 + quad*4 + rg;
              const int k = k0 + nj*16 + l4;
              if (k > q) s[mi][nj][rg] = -1e30f;
            }
      }
      // row max over 64 keys
      float mx[2][4];
      #pragma unroll
      for (int mi = 0; mi < 2; ++mi)
        #pragma unroll
        for (int rg = 0; rg < 4; ++rg) {
          float m0 = fmaxf(fmaxf(s[mi][0][rg], s[mi][1][rg]),
                           fmaxf(s[mi][2][rg], s[mi][3][rg]));
          #pragma unroll
          for (int off = 1; off < 16; off <<= 1) m0 = fmaxf(m0, __shfl_xor(m0, off, 64));
          mx[mi][rg] = m0;
        }
      // online-softmax update
      float al[2][4];
      #pragma unroll
      for (int mi = 0; mi < 2; ++mi)
        #pragma unroll
        for (int rg = 0; rg < 4; ++rg) {
          const float mn = fmaxf(m_run[mi][rg], mx[mi][rg] * cs);
          al[mi][rg] = __builtin_amdgcn_exp2f(m_run[mi][rg] - mn);
          m_run[mi][rg] = mn;
        }
      float rs[2][4] = {};
      #pragma unroll
      for (int mi = 0; mi < 2; ++mi)
        #pragma unroll
        for (int nj = 0; nj < 4; ++nj)
          #pragma unroll
          for (int rg = 0; rg < 4; ++rg) {
            const float p = __builtin_amdgcn_exp2f(s[mi][nj][rg] * cs - m_run[mi][rg]);
            rs[mi][rg] += p;
            Pb[wave][mi*16 + quad*4 + rg][nj*16 + l4] = f2bf(p);
          }
      #pragma unroll
      for (int mi = 0; mi < 2; ++mi)
        #pragma unroll
        for (int rg = 0; rg < 4; ++rg) {
          float r0 = rs[mi][rg];
          #pragma unroll
          for (int off = 1; off < 16; off <<= 1) r0 += __shfl_xor(r0, off, 64);
          l_run[mi][rg] = l_run[mi][rg] * al[mi][rg] + r0;
          #pragma unroll
          for (int ni = 0; ni < 4; ++ni) o[mi][ni][rg] *= al[mi][rg];
        }
      // O += P V   (P from LDS in A layout, V^T from LDS in B layout)
      #pragma unroll
      for (int kf2 = 0; kf2 < 2; ++kf2) {
        s16x8 pa[2];
        #pragma unroll
        for (int mi = 0; mi < 2; ++mi)
          pa[mi] = *(const s16x8*)&Pb[wave][mi*16 + l4][kf2*32 + quad*8];
        #pragma unroll
        for (int ni = 0; ni < 4; ++ni) {
          const s16x8 vb = *(const s16x8*)&Vt[ni*16 + l4][kf2*32 + quad*8];
          #pragma unroll
          for (int mi = 0; mi < 2; ++mi)
            o[mi][ni] = __builtin_amdgcn_mfma_f32_16x16x32_bf16(pa[mi], vb, o[mi][ni], 0, 0, 0);
        }
      }
    }
  }

  #pragma unroll
  for (int mi = 0; mi < 2; ++mi)
    #pragma unroll
    for (int rg = 0; rg < 4; ++rg) {
      const float inv = 1.0f / l_run[mi][rg];
      const size_t row = (size_t)b * TT + qw + mi*16 + quad*4 + rg;
      #pragma unroll
      for (int ni = 0; ni < 4; ++ni)
        ao[row * DM + h*HD + ni*16 + l4] = f2bf(o[mi][ni][rg] * inv);
    }
}

extern "C" void kernel_launch(void* const* d_in, const int* in_sizes, int n_in,
                              void* d_out, int out_size, void* d_ws, size_t ws_size,
                              hipStream_t stream) {
  (void)in_sizes; (void)n_in; (void)out_size; (void)ws_size;
  const float* x  = (const float*)d_in[0];
  const float* nw = (const float*)d_in[1];
  const float* Wq = (const float*)d_in[2];
  const float* Wk = (const float*)d_in[3];
  const float* Wv = (const float*)d_in[4];
  const float* Wo = (const float*)d_in[5];
  const float* W1 = (const float*)d_in[6];
  const float* W2 = (const float*)d_in[7];

  char* ws = (char*)d_ws;
  u16*   xn     = (u16*)(ws);                          //  8 MB  [BT][1024]
  u16*   wqkv_t = (u16*)(ws + ((size_t)8  << 20));     //  6 MB  [3072][1024]
  u16*   wo_t   = (u16*)(ws + ((size_t)14 << 20));     //  2 MB  [1024][1024]
  u16*   w1_t   = (u16*)(ws + ((size_t)16 << 20));     //  8 MB  [4096][1024]
  u16*   w2_t   = (u16*)(ws + ((size_t)24 << 20));     //  8 MB  [1024][4096]
  u16*   qkv    = (u16*)(ws + ((size_t)32 << 20));     // 24 MB  [BT][3072]
  u16*   attn_o = (u16*)(ws + ((size_t)56 << 20));     //  8 MB  [BT][1024]
  float* proj   = (float*)(ws + ((size_t)64 << 20));   // 16 MB  [BT][1024]
  u16*   ff1    = (u16*)(ws + ((size_t)80 << 20));     // 32 MB  [BT][4096]

  rmsnorm_k<<<BT, 256, 0, stream>>>(x, nw, xn);
  const dim3 tb(32, 8);
  wtrans_k<<<dim3(32, 32),  tb, 0, stream>>>(Wq, wqkv_t,                      1024, 1024);
  wtrans_k<<<dim3(32, 32),  tb, 0, stream>>>(Wk, wqkv_t + (size_t)1024*1024,  1024, 1024);
  wtrans_k<<<dim3(32, 32),  tb, 0, stream>>>(Wv, wqkv_t + (size_t)2048*1024,  1024, 1024);
  wtrans_k<<<dim3(32, 32),  tb, 0, stream>>>(Wo, wo_t,                        1024, 1024);
  wtrans_k<<<dim3(128, 32), tb, 0, stream>>>(W1, w1_t,                        1024, 4096);
  wtrans_k<<<dim3(32, 128), tb, 0, stream>>>(W2, w2_t,                        4096, 1024);

  gemm_k<0><<<dim3(24, 32), 256, 0, stream>>>(xn,     wqkv_t, qkv,   1024, 3072, nullptr, nullptr);
  attn_k<<<dim3(16, 32), 256, 0, stream>>>(qkv, attn_o);
  gemm_k<2><<<dim3(8, 32),  256, 0, stream>>>(attn_o, wo_t,   proj,  1024, 1024, nullptr, nullptr);
  gemm_k<1><<<dim3(32, 32), 256, 0, stream>>>(xn,     w1_t,   ff1,   1024, 4096, nullptr, nullptr);
  gemm_k<3><<<dim3(8, 32),  256, 0, stream>>>(ff1,    w2_t,   d_out, 4096, 1024, x, proj);
}

// Round 2
// 425.029 us; speedup vs baseline: 1.0539x; 1.0539x over previous
//
#include <hip/hip_runtime.h>

#define DM   1024
#define DFF  4096
#define NH   16
#define HD   64
#define TT   2048
#define BT   4096   // B*T

typedef unsigned short u16;
typedef unsigned int   u32;
typedef __attribute__((ext_vector_type(8))) short s16x8;
typedef __attribute__((ext_vector_type(4))) float f32x4;

__device__ __forceinline__ u16 f2bf(float f) {
  u32 u = __builtin_bit_cast(u32, f);
  u += 0x7fffu + ((u >> 16) & 1u);
  return (u16)(u >> 16);
}

// async global->LDS, 16B per lane. HW semantics: dest = wave-uniform base + lane*16.
__device__ __forceinline__ void gl2lds16(const void* g, void* l) {
  __builtin_amdgcn_global_load_lds((__attribute__((address_space(1))) void*)(g),
                                   (__attribute__((address_space(3))) void*)(l),
                                   16, 0, 0);
}

// ---------------- RMSNorm: x fp32 [BT][DM] -> xn bf16 ----------------
__global__ __launch_bounds__(256) void rmsnorm_k(const float* __restrict__ x,
                                                 const float* __restrict__ w,
                                                 u16* __restrict__ xn) {
  const int row = blockIdx.x;
  const int t = threadIdx.x;
  const float4 v = ((const float4*)(x + (size_t)row * DM))[t];
  float ss = v.x*v.x + v.y*v.y + v.z*v.z + v.w*v.w;
  #pragma unroll
  for (int off = 32; off; off >>= 1) ss += __shfl_xor(ss, off, 64);
  __shared__ float red[4];
  if ((t & 63) == 0) red[t >> 6] = ss;
  __syncthreads();
  const float tot = red[0] + red[1] + red[2] + red[3];
  const float r = __builtin_amdgcn_rsqf(tot * (1.0f / DM) + 1.1920929e-7f);
  const float4 wv = ((const float4*)w)[t];
  u16* o = xn + (size_t)row * DM + t * 4;
  o[0] = f2bf(v.x * r * wv.x);
  o[1] = f2bf(v.y * r * wv.y);
  o[2] = f2bf(v.z * r * wv.z);
  o[3] = f2bf(v.w * r * wv.w);
}

// ------------- weight transpose+cvt: W fp32 [K][N] -> Wt bf16 [N][K] -------------
__global__ __launch_bounds__(256) void wtrans_k(const float* __restrict__ W,
                                                u16* __restrict__ Wt,
                                                int K, int N) {
  __shared__ float tile[32][33];
  const int n0 = blockIdx.x * 32, k0 = blockIdx.y * 32;
  const int tx = threadIdx.x, ty = threadIdx.y;  // (32,8)
  #pragma unroll
  for (int i = 0; i < 4; ++i)
    tile[ty + i*8][tx] = W[(size_t)(k0 + ty + i*8) * N + n0 + tx];
  __syncthreads();
  #pragma unroll
  for (int i = 0; i < 4; ++i)
    Wt[(size_t)(n0 + ty + i*8) * K + k0 + tx] = f2bf(tile[tx][ty + i*8]);
}

// ---------------- GEMM: C[M][N] = A[M][K] * Bt[N][K]^T  (bf16 in, fp32 acc) -----
// MODE 1: silu->bf16;  2: out fp32;  3: out fp32 = acc+add1+add2
// MODE 4: qkv: cols<2048 -> bf16 [M][2048]; cols>=2048 (V) -> transposed bf16
//         Cv2[(b*16+h)*64 + d][2048] (per-b,h V^T for attention B-fragments)
template <int MODE>
__global__ __launch_bounds__(256, 2) void gemm_k(const u16* __restrict__ A,
                                                 const u16* __restrict__ Bt,
                                                 void* __restrict__ Cv,
                                                 int K, int N,
                                                 const float* __restrict__ add1,
                                                 const float* __restrict__ add2,
                                                 void* __restrict__ Cv2) {
  __shared__ u16 sA[128 * 32];
  __shared__ u16 sB[128 * 32];
  const int t = threadIdx.x;
  const int lane = t & 63, wave = t >> 6;
  const int quad = lane >> 4, l4 = lane & 15;
  const int wy = wave >> 1, wx = wave & 1;
  const size_t mBase = (size_t)blockIdx.y * 128;
  const size_t nBase = (size_t)blockIdx.x * 128;
  const int r  = t >> 2;          // 0..63
  const int c8 = (t & 3) * 8;     // 0,8,16,24
  const u16* Ag0 = A + (mBase + r) * K + c8;
  const u16* Ag1 = Ag0 + (size_t)64 * K;
  const u16* Bg0 = Bt + (nBase + r) * K + c8;
  const u16* Bg1 = Bg0 + (size_t)64 * K;
  char* sAb = (char*)sA + (wave << 10);   // wave-uniform LDS base
  char* sBb = (char*)sB + (wave << 10);

  f32x4 acc[4][4];
  #pragma unroll
  for (int i = 0; i < 4; ++i)
    #pragma unroll
    for (int j = 0; j < 4; ++j)
      acc[i][j] = (f32x4)0.0f;

  for (int k0 = 0; k0 < K; k0 += 32) {
    __syncthreads();
    gl2lds16(Ag0 + k0, sAb);
    gl2lds16(Ag1 + k0, sAb + 4096);
    gl2lds16(Bg0 + k0, sBb);
    gl2lds16(Bg1 + k0, sBb + 4096);
    __syncthreads();
    s16x8 af[4], bfr[4];
    #pragma unroll
    for (int i = 0; i < 4; ++i)
      af[i] = *(const s16x8*)&sA[(wy*64 + i*16 + l4) * 32 + quad*8];
    #pragma unroll
    for (int j = 0; j < 4; ++j)
      bfr[j] = *(const s16x8*)&sB[(wx*64 + j*16 + l4) * 32 + quad*8];
    #pragma unroll
    for (int i = 0; i < 4; ++i)
      #pragma unroll
      for (int j = 0; j < 4; ++j)
        acc[i][j] = __builtin_amdgcn_mfma_f32_16x16x32_bf16(af[i], bfr[j], acc[i][j], 0, 0, 0);
  }

  #pragma unroll
  for (int i = 0; i < 4; ++i) {
    const size_t row0 = mBase + wy*64 + i*16 + quad*4;
    #pragma unroll
    for (int j = 0; j < 4; ++j) {
      const int col = (int)nBase + wx*64 + j*16 + l4;
      if (MODE == 4 && col >= 2048) {
        // V part: write transposed, 4 contiguous tokens packed per store
        const int cv = col - 2048, hh = cv >> 6, dd = cv & 63;
        const int bb = (int)(row0 >> 11), t0 = (int)(row0 & 2047);
        ushort4 pk;
        pk.x = f2bf(acc[i][j][0]); pk.y = f2bf(acc[i][j][1]);
        pk.z = f2bf(acc[i][j][2]); pk.w = f2bf(acc[i][j][3]);
        *(ushort4*)((u16*)Cv2 + ((size_t)((bb*16 + hh)*64 + dd)) * 2048 + t0) = pk;
      } else {
        #pragma unroll
        for (int rg = 0; rg < 4; ++rg) {
          float v = acc[i][j][rg];
          if (MODE == 4) {
            ((u16*)Cv)[(row0 + rg) * 2048 + col] = f2bf(v);
          } else {
            const size_t idx = (row0 + rg) * (size_t)N + col;
            if (MODE == 1) {
              v = v / (1.0f + __expf(-v));
              ((u16*)Cv)[idx] = f2bf(v);
            } else if (MODE == 2) {
              ((float*)Cv)[idx] = v;
            } else {
              ((float*)Cv)[idx] = v + add1[idx] + add2[idx];
            }
          }
        }
      }
    }
  }
}

// ---------------- causal flash attention, barrier-free ----------------
// qk bf16 [BT][2048] (cols: q|k per head), vtg bf16 [32 bh][64 d][2048 t]
// out ao bf16 [BT][DM]. One wave per block; 32 q-rows per wave.
__global__ __launch_bounds__(64) void attn_k(const u16* __restrict__ qk,
                                             const u16* __restrict__ vtg,
                                             u16* __restrict__ ao) {
  const int bh = blockIdx.x, b = bh >> 4, h = bh & 15;
  // balanced heavy-first q-tile swizzle: groups of 8 y's (one dispatch round
  // per CU-group) alternate ascending/descending so per-CU work sums constant.
  const int y = blockIdx.y;
  const int kg = y >> 3, rr = y & 7;
  const int qt = 63 - (kg*8 + ((kg & 1) ? (7 - rr) : rr));
  const int qw = qt * 32;                  // this wave's 32 q rows
  const int t = threadIdx.x, lane = t & 63;
  const int quad = lane >> 4, l4 = lane & 15;
  const u16* Qp = qk + (size_t)b * TT * 2048 + h * HD;
  const u16* Kp = Qp + 1024;
  const u16* Vp = vtg + (size_t)bh * 64 * 2048;

  __shared__ u16 Pb[32][72];               // per-wave P round-trip buffer

  // Q fragments (A layout): lane holds Q[qw+mi*16+l4][kf*32+quad*8 .. +7]
  s16x8 qf[2][2];
  #pragma unroll
  for (int mi = 0; mi < 2; ++mi)
    #pragma unroll
    for (int kf = 0; kf < 2; ++kf)
      qf[mi][kf] = *(const s16x8*)(Qp + (size_t)(qw + mi*16 + l4) * 2048 + kf*32 + quad*8);

  float m_run[2][4], l_run[2][4];
  f32x4 o[2][4];
  #pragma unroll
  for (int mi = 0; mi < 2; ++mi) {
    #pragma unroll
    for (int rg = 0; rg < 4; ++rg) { m_run[mi][rg] = -1e30f; l_run[mi][rg] = 0.0f; }
    #pragma unroll
    for (int ni = 0; ni < 4; ++ni) o[mi][ni] = (f32x4)0.0f;
  }

  const int nkt = (qw + 31) / 64 + 1;      // causal: keys 0 .. qw+31
  const float cs = 0.18033688011f;         // (1/sqrt(64)) * log2(e)

  for (int kt = 0; kt < nkt; ++kt) {
    const int k0 = kt * 64;

    // V fragments direct from global V^T (B layout), hoisted for overlap
    s16x8 vb[2][4];
    #pragma unroll
    for (int kf2 = 0; kf2 < 2; ++kf2)
      #pragma unroll
      for (int ni = 0; ni < 4; ++ni)
        vb[kf2][ni] = *(const s16x8*)(Vp + (size_t)(ni*16 + l4) * 2048 + k0 + kf2*32 + quad*8);

    // S = Q K^T   (C layout: row q = quad*4+rg, col key = l4)
    f32x4 s[2][4];
    #pragma unroll
    for (int nj = 0; nj < 4; ++nj) {
      const u16* kr = Kp + (size_t)(k0 + nj*16 + l4) * 2048 + quad*8;
      const s16x8 kf0 = *(const s16x8*)kr;
      const s16x8 kf1 = *(const s16x8*)(kr + 32);
      #pragma unroll
      for (int mi = 0; mi < 2; ++mi) {
        f32x4 a = (f32x4)0.0f;
        a = __builtin_amdgcn_mfma_f32_16x16x32_bf16(qf[mi][0], kf0, a, 0, 0, 0);
        a = __builtin_amdgcn_mfma_f32_16x16x32_bf16(qf[mi][1], kf1, a, 0, 0, 0);
        s[mi][nj] = a;
      }
    }
    if (k0 + 63 > qw) {  // causal mask needed on this (diagonal) tile
      #pragma unroll
      for (int mi = 0; mi < 2; ++mi)
        #pragma unroll
        for (int nj = 0; nj < 4; ++nj)
          #pragma unroll
          for (int rg = 0; rg < 4; ++rg) {
            const int q = qw + mi*16 + quad*4 + rg;
            const int k = k0 + nj*16 + l4;
            if (k > q) s[mi][nj][rg] = -1e30f;
          }
    }
    // row max over 64 keys
    float mx[2][4];
    #pragma unroll
    for (int mi = 0; mi < 2; ++mi)
      #pragma unroll
      for (int rg = 0; rg < 4; ++rg) {
        float m0 = fmaxf(fmaxf(s[mi][0][rg], s[mi][1][rg]),
                         fmaxf(s[mi][2][rg], s[mi][3][rg]));
        #pragma unroll
        for (int off = 1; off < 16; off <<= 1) m0 = fmaxf(m0, __shfl_xor(m0, off, 64));
        mx[mi][rg] = m0;
      }
    // online-softmax update
    float al[2][4];
    #pragma unroll
    for (int mi = 0; mi < 2; ++mi)
      #pragma unroll
      for (int rg = 0; rg < 4; ++rg) {
        const float mn = fmaxf(m_run[mi][rg], mx[mi][rg] * cs);
        al[mi][rg] = __builtin_amdgcn_exp2f(m_run[mi][rg] - mn);
        m_run[mi][rg] = mn;
      }
    float rs[2][4] = {};
    #pragma unroll
    for (int mi = 0; mi < 2; ++mi)
      #pragma unroll
      for (int nj = 0; nj < 4; ++nj)
        #pragma unroll
        for (int rg = 0; rg < 4; ++rg) {
          const float p = __builtin_amdgcn_exp2f(s[mi][nj][rg] * cs - m_run[mi][rg]);
          rs[mi][rg] += p;
          Pb[mi*16 + quad*4 + rg][nj*16 + l4] = f2bf(p);
        }
    #pragma unroll
    for (int mi = 0; mi < 2; ++mi)
      #pragma unroll
      for (int rg = 0; rg < 4; ++rg) {
        float r0 = rs[mi][rg];
        #pragma unroll
        for (int off = 1; off < 16; off <<= 1) r0 += __shfl_xor(r0, off, 64);
        l_run[mi][rg] = l_run[mi][rg] * al[mi][rg] + r0;
        #pragma unroll
        for (int ni = 0; ni < 4; ++ni) o[mi][ni][rg] *= al[mi][rg];
      }
    // O += P V   (P from per-wave LDS in A layout; V from registers)
    #pragma unroll
    for (int kf2 = 0; kf2 < 2; ++kf2) {
      s16x8 pa[2];
      #pragma unroll
      for (int mi = 0; mi < 2; ++mi)
        pa[mi] = *(const s16x8*)&Pb[mi*16 + l4][kf2*32 + quad*8];
      #pragma unroll
      for (int ni = 0; ni < 4; ++ni)
        #pragma unroll
        for (int mi = 0; mi < 2; ++mi)
          o[mi][ni] = __builtin_amdgcn_mfma_f32_16x16x32_bf16(pa[mi], vb[kf2][ni], o[mi][ni], 0, 0, 0);
    }
  }

  #pragma unroll
  for (int mi = 0; mi < 2; ++mi)
    #pragma unroll
    for (int rg = 0; rg < 4; ++rg) {
      const float inv = 1.0f / l_run[mi][rg];
      const size_t row = (size_t)b * TT + qw + mi*16 + quad*4 + rg;
      #pragma unroll
      for (int ni = 0; ni < 4; ++ni)
        ao[row * DM + h*HD + ni*16 + l4] = f2bf(o[mi][ni][rg] * inv);
    }
}

extern "C" void kernel_launch(void* const* d_in, const int* in_sizes, int n_in,
                              void* d_out, int out_size, void* d_ws, size_t ws_size,
                              hipStream_t stream) {
  (void)in_sizes; (void)n_in; (void)out_size; (void)ws_size;
  const float* x  = (const float*)d_in[0];
  const float* nw = (const float*)d_in[1];
  const float* Wq = (const float*)d_in[2];
  const float* Wk = (const float*)d_in[3];
  const float* Wv = (const float*)d_in[4];
  const float* Wo = (const float*)d_in[5];
  const float* W1 = (const float*)d_in[6];
  const float* W2 = (const float*)d_in[7];

  char* ws = (char*)d_ws;
  u16*   xn     = (u16*)(ws);                          //  8 MB  [BT][1024]
  u16*   wqkv_t = (u16*)(ws + ((size_t)8  << 20));     //  6 MB  [3072][1024]
  u16*   wo_t   = (u16*)(ws + ((size_t)14 << 20));     //  2 MB  [1024][1024]
  u16*   w1_t   = (u16*)(ws + ((size_t)16 << 20));     //  8 MB  [4096][1024]
  u16*   w2_t   = (u16*)(ws + ((size_t)24 << 20));     //  8 MB  [1024][4096]
  u16*   qkb    = (u16*)(ws + ((size_t)32 << 20));     // 16 MB  [BT][2048]  (q|k)
  u16*   vtg    = (u16*)(ws + ((size_t)48 << 20));     //  8 MB  [32][64][2048] V^T
  u16*   attn_o = (u16*)(ws + ((size_t)56 << 20));     //  8 MB  [BT][1024]
  float* proj   = (float*)(ws + ((size_t)64 << 20));   // 16 MB  [BT][1024]
  u16*   ff1    = (u16*)(ws + ((size_t)80 << 20));     // 32 MB  [BT][4096]

  rmsnorm_k<<<BT, 256, 0, stream>>>(x, nw, xn);
  const dim3 tb(32, 8);
  wtrans_k<<<dim3(32, 32),  tb, 0, stream>>>(Wq, wqkv_t,                      1024, 1024);
  wtrans_k<<<dim3(32, 32),  tb, 0, stream>>>(Wk, wqkv_t + (size_t)1024*1024,  1024, 1024);
  wtrans_k<<<dim3(32, 32),  tb, 0, stream>>>(Wv, wqkv_t + (size_t)2048*1024,  1024, 1024);
  wtrans_k<<<dim3(32, 32),  tb, 0, stream>>>(Wo, wo_t,                        1024, 1024);
  wtrans_k<<<dim3(128, 32), tb, 0, stream>>>(W1, w1_t,                        1024, 4096);
  wtrans_k<<<dim3(32, 128), tb, 0, stream>>>(W2, w2_t,                        4096, 1024);

  gemm_k<4><<<dim3(24, 32), 256, 0, stream>>>(xn,     wqkv_t, qkb,  1024, 3072, nullptr, nullptr, vtg);
  attn_k<<<dim3(32, 64), 64, 0, stream>>>(qkb, vtg, attn_o);
  gemm_k<2><<<dim3(8, 32),  256, 0, stream>>>(attn_o, wo_t,   proj, 1024, 1024, nullptr, nullptr, nullptr);
  gemm_k<1><<<dim3(32, 32), 256, 0, stream>>>(xn,     w1_t,   ff1,  1024, 4096, nullptr, nullptr, nullptr);
  gemm_k<3><<<dim3(8, 32),  256, 0, stream>>>(ff1,    w2_t,   d_out, 4096, 1024, x, proj, nullptr);
}